// Round 11
// baseline (275.524 us; speedup 1.0000x reference)
//
#include <hip/hip_runtime.h>
#include <hip/hip_bf16.h>
#include <math.h>
#include <stdint.h>

#define DDIM 512
#define QN   256
#define QH   128            // queries per half
#define CROWS 256           // rows per chunk = 8 waves x 32
#define WAVES 8
#define NT   512
#define KNN  5
#define NKS  16             // K steps of 32
#define BIGF 3.0e38f

typedef __attribute__((ext_vector_type(8))) short bf16x8;
typedef __attribute__((ext_vector_type(4))) float f32x4;

// async global->LDS: dest = wave-uniform base (HW adds lane*16); source is
// per-lane. qfrag is pre-permuted to lane order so each gload reads 1KB linear.
__device__ __forceinline__ void gload16(const void* g, void* l) {
    __builtin_amdgcn_global_load_lds(
        (const __attribute__((address_space(1))) void*)g,
        (__attribute__((address_space(3))) void*)l, 16, 0, 0);
}

__device__ __forceinline__ bf16x8 pack8(float4 a, float4 b) {
    union { bf16x8 v; __hip_bfloat162 h[4]; } u;
    u.h[0] = __float22bfloat162_rn(make_float2(a.x, a.y));
    u.h[1] = __float22bfloat162_rn(make_float2(a.z, a.w));
    u.h[2] = __float22bfloat162_rn(make_float2(b.x, b.y));
    u.h[3] = __float22bfloat162_rn(make_float2(b.z, b.w));
    return u.v;
}
__device__ __forceinline__ float sq8(float4 a, float4 b, float s) {
    s = fmaf(a.x,a.x,s); s = fmaf(a.y,a.y,s); s = fmaf(a.z,a.z,s); s = fmaf(a.w,a.w,s);
    s = fmaf(b.x,b.x,s); s = fmaf(b.y,b.y,s); s = fmaf(b.z,b.z,s); s = fmaf(b.w,b.w,s);
    return s;
}

// Packed top-5 insert (idx in low 8 mantissa bits). Static indices only.
__device__ __forceinline__ void t5p_insert(float (&s)[KNN], float v) {
    if (v < s[4]) {
        s[4] = v;
        if (s[4] < s[3]) { float t = s[3]; s[3] = s[4]; s[4] = t; }
        if (s[3] < s[2]) { float t = s[2]; s[2] = s[3]; s[3] = t; }
        if (s[2] < s[1]) { float t = s[1]; s[1] = s[2]; s[2] = t; }
        if (s[1] < s[0]) { float t = s[0]; s[0] = s[1]; s[1] = t; }
    }
}
__device__ __forceinline__ void t5_insert(float (&s)[KNN], int (&ix)[KNN], float v, int vi) {
    if (v < s[4]) {
        s[4] = v; ix[4] = vi;
        if (s[4] < s[3]) { float t = s[3]; s[3] = s[4]; s[4] = t; int u = ix[3]; ix[3] = ix[4]; ix[4] = u; }
        if (s[3] < s[2]) { float t = s[2]; s[2] = s[3]; s[3] = t; int u = ix[2]; ix[2] = ix[3]; ix[3] = u; }
        if (s[2] < s[1]) { float t = s[1]; s[1] = s[2]; s[2] = t; int u = ix[1]; ix[1] = ix[2]; ix[2] = u; }
        if (s[1] < s[0]) { float t = s[0]; s[0] = s[1]; s[1] = t; int u = ix[0]; ix[0] = ix[1]; ix[1] = u; }
    }
}

// Phase 0: queries f32 -> bf16 in LANE-ORDER fragment layout:
// qfrag[qb][ks][lane]*16B, lane = lq*16 + l15  <->  (q = qb*16+l15, k = ks*32+lq*8)
__global__ void conv_q(const float* __restrict__ emb, unsigned short* __restrict__ qfrag) {
    int t = blockIdx.x * 256 + threadIdx.x;     // 16384 threads: [qb][ks][lane]
    int l   = t & 63;
    int ks  = (t >> 6) & 15;
    int qb  = t >> 10;
    int q   = qb * 16 + (l & 15);
    int k   = ks * 32 + (l >> 4) * 8;
    const float* p = emb + (size_t)q * DDIM + k;
    float4 f0 = *(const float4*)(p);
    float4 f1 = *(const float4*)(p + 4);
    *(bf16x8*)(qfrag + (size_t)t * 8) = pack8(f0, f1);
}

// Phase A: block = (chunk of 256 rows, q-half of 128). The q-half's FULL B
// (128 KB, lane-order frags) is staged into LDS once; the K-loop then runs
// BARRIER-FREE: A streams HBM->reg->bf16 (each mem byte read once per half),
// B-frags stream from read-only LDS (contiguous per wave, conflict-free).
__global__ __launch_bounds__(NT, 2) void knn_partial(
        const float* __restrict__ mem, const unsigned short* __restrict__ qfrag,
        float* __restrict__ cand, int N, int NCH) {
    __shared__ union {
        char  b[QH * DDIM * 2];         // 128 KB: frag (qb_local*16+ks)*1024
        float mbuf[WAVES][QH][KNN];     // 20 KB (epilogue)
    } sm;
    __shared__ float smsq[CROWS];

    const int tid  = threadIdx.x;
    const int lane = tid & 63;
    const int w    = tid >> 6;          // 0..7
    const int l15  = lane & 15;
    const int lq   = lane >> 4;         // k-slice 0..3
    const int chunk = blockIdx.x >> 1;
    const int h     = blockIdx.x & 1;   // q-half
    const int rbase = chunk * CROWS;

    // ---- stage B-half once: wave w stages qb_local = w (16 frags of 1 KB)
    {
        const char* src = (const char*)qfrag + ((size_t)(h * 8 + w) * 16) * 1024 + lane * 16;
        char* dst = sm.b + (w * 16) * 1024;
#pragma unroll
        for (int i = 0; i < 16; ++i)
            gload16(src + i * 1024, dst + i * 1024);
    }

    // A rows: wave w owns rows rbase + w*32 .. +31 (read once per half)
    int r0 = rbase + w * 32 + l15;      if (r0 >= N) r0 = N - 1;
    int r1 = rbase + w * 32 + 16 + l15; if (r1 >= N) r1 = N - 1;
    const float* pA0 = mem + (size_t)r0 * DDIM + lq * 8;
    const float* pA1 = mem + (size_t)r1 * DDIM + lq * 8;

    f32x4 acc[2][8];
    const f32x4 z4 = {0.f, 0.f, 0.f, 0.f};
#pragma unroll
    for (int rf = 0; rf < 2; ++rf)
#pragma unroll
        for (int g = 0; g < 8; ++g) acc[rf][g] = z4;
    float sq0 = 0.f, sq1 = 0.f;

    // first A slab
    float4 c00 = *(const float4*)(pA0), c01 = *(const float4*)(pA0 + 4);
    float4 c10 = *(const float4*)(pA1), c11 = *(const float4*)(pA1 + 4);

    __syncthreads();                    // B staged (compiler drains vmcnt here)

    for (int ks = 0; ks < NKS; ++ks) {
        float4 n00, n01, n10, n11;
        if (ks + 1 < NKS) {             // prefetch next A slab (no barrier ahead)
            const float* a0 = pA0 + (ks + 1) * 32;
            const float* a1 = pA1 + (ks + 1) * 32;
            n00 = *(const float4*)(a0); n01 = *(const float4*)(a0 + 4);
            n10 = *(const float4*)(a1); n11 = *(const float4*)(a1 + 4);
        }
        bf16x8 a0 = pack8(c00, c01);
        bf16x8 a1 = pack8(c10, c11);
        sq0 = sq8(c00, c01, sq0);
        sq1 = sq8(c10, c11, sq1);
        const char* bp = sm.b + ks * 1024 + lane * 16;
#pragma unroll
        for (int g = 0; g < 8; ++g) {   // one B-frag live at a time
            bf16x8 br = *(const bf16x8*)(bp + g * 16384);
            acc[0][g] = __builtin_amdgcn_mfma_f32_16x16x32_bf16(a0, br, acc[0][g], 0, 0, 0);
            acc[1][g] = __builtin_amdgcn_mfma_f32_16x16x32_bf16(a1, br, acc[1][g], 0, 0, 0);
        }
        if (ks + 1 < NKS) { c00 = n00; c01 = n01; c10 = n10; c11 = n11; }
    }

    // ||m||^2 per row (reduce k-slices across lq)
    sq0 += __shfl_xor(sq0, 16); sq0 += __shfl_xor(sq0, 32);
    sq1 += __shfl_xor(sq1, 16); sq1 += __shfl_xor(sq1, 32);
    if (lane < 16) {
        smsq[w * 32 + lane]      = sq0;
        smsq[w * 32 + 16 + lane] = sq1;
    }
    __syncthreads();                    // all B reads done; mbuf may alias B
    float rsq0[4], rsq1[4];
    *(float4*)rsq0 = *(const float4*)&smsq[w * 32 + lq * 4];
    *(float4*)rsq1 = *(const float4*)&smsq[w * 32 + 16 + lq * 4];

    // epilogue: per q-frag g (8 per wave): packed scores over this wave's 32
    // rows -> lane top5 -> shfl merge -> mbuf[w]
#pragma unroll
    for (int g = 0; g < 8; ++g) {
        float ts[KNN] = {BIGF, BIGF, BIGF, BIGF, BIGF};
#pragma unroll
        for (int e = 0; e < 4; ++e) {
            int rl0 = w * 32 + lq * 4 + e;          // chunk-local row (frag 0)
            if (rbase + rl0 < N) {
                float sc = fmaf(-2.f, acc[0][g][e], rsq0[e]);
                t5p_insert(ts, __int_as_float((__float_as_int(sc) & ~255) | rl0));
            }
            int rl1 = rl0 + 16;                     // frag 1
            if (rbase + rl1 < N) {
                float sc = fmaf(-2.f, acc[1][g][e], rsq1[e]);
                t5p_insert(ts, __int_as_float((__float_as_int(sc) & ~255) | rl1));
            }
        }
#pragma unroll
        for (int x = 16; x <= 32; x <<= 1) {
            float os[KNN];
#pragma unroll
            for (int c = 0; c < KNN; ++c) os[c] = __shfl_xor(ts[c], x);
#pragma unroll
            for (int c = 0; c < KNN; ++c) t5p_insert(ts, os[c]);
        }
        if (lane < 16) {
#pragma unroll
            for (int c = 0; c < KNN; ++c) sm.mbuf[w][g * 16 + lane][c] = ts[c];
        }
    }
    __syncthreads();
    if (tid < QH) {      // q-local tid: merge 8 waves; cand[q][chunk][5]
        float fsv[KNN] = {BIGF, BIGF, BIGF, BIGF, BIGF};
#pragma unroll
        for (int ww = 0; ww < WAVES; ++ww)
#pragma unroll
            for (int c = 0; c < KNN; ++c)
                t5p_insert(fsv, sm.mbuf[ww][tid][c]);
        float* dst = cand + ((size_t)(h * QH + tid) * NCH + chunk) * KNN;
#pragma unroll
        for (int c = 0; c < KNN; ++c) dst[c] = fsv[c];
    }
}

// Phase B: one wave per query: global top-5 over NCH*5 packed candidates,
// gather rows, exact f32 distances (immune to bf16/packing jitter), sum.
__global__ void knn_merge_exact(const float* __restrict__ emb, const float* __restrict__ mem,
                                const float* __restrict__ cand, float* __restrict__ qsum,
                                int Q, int NCH) {
    const int q = blockIdx.x;
    const int lane = threadIdx.x;  // 64
    float fs[KNN] = {BIGF, BIGF, BIGF, BIGF, BIGF};
    int   fi[KNN] = {0, 0, 0, 0, 0};
    const float* qc = cand + (size_t)q * NCH * KNN;
    for (int c = lane; c < NCH; c += 64) {
        const float* p = qc + (size_t)c * KNN;
#pragma unroll
        for (int k = 0; k < KNN; ++k) {
            float pk = p[k];
            int idx = c * CROWS + (__float_as_int(pk) & 255);
            t5_insert(fs, fi, pk, idx);
        }
    }
    __shared__ float2 ls[64][KNN];
    __shared__ int sel[KNN];
#pragma unroll
    for (int k = 0; k < KNN; ++k) ls[lane][k] = make_float2(fs[k], __int_as_float(fi[k]));
    __syncthreads();
    if (lane == 0) {
        float gs[KNN] = {BIGF, BIGF, BIGF, BIGF, BIGF};
        int   gi[KNN] = {0, 0, 0, 0, 0};
        for (int l = 0; l < 64; ++l)
#pragma unroll
            for (int k = 0; k < KNN; ++k)
                t5_insert(gs, gi, ls[l][k].x, __float_as_int(ls[l][k].y));
#pragma unroll
        for (int k = 0; k < KNN; ++k) sel[k] = gi[k];
    }
    __syncthreads();
    const float4* qp = (const float4*)(emb + (size_t)q * DDIM);
    float4 q0 = qp[lane * 2], q1 = qp[lane * 2 + 1];
    float ssum = 0.f;
    for (int k = 0; k < KNN; ++k) {
        const float4* mp = (const float4*)(mem + (size_t)sel[k] * DDIM);
        float4 m0 = mp[lane * 2], m1 = mp[lane * 2 + 1];
        float d0 = m0.x - q0.x, d1 = m0.y - q0.y, d2 = m0.z - q0.z, d3 = m0.w - q0.w;
        float d4 = m1.x - q1.x, d5 = m1.y - q1.y, d6 = m1.z - q1.z, d7 = m1.w - q1.w;
        float t = d0*d0 + d1*d1 + d2*d2 + d3*d3 + d4*d4 + d5*d5 + d6*d6 + d7*d7;
#pragma unroll
        for (int off = 32; off > 0; off >>= 1) t += __shfl_down(t, off);
        if (lane == 0) ssum += sqrtf(t);
    }
    if (lane == 0) qsum[q] = ssum;
}

__global__ void knn_reduce(const float* __restrict__ qsum, float* __restrict__ out, int Q) {
    const int lane = threadIdx.x;
    float v = 0.f;
    for (int i = lane; i < Q; i += 64) v += qsum[i];
#pragma unroll
    for (int off = 32; off > 0; off >>= 1) v += __shfl_down(v, off);
    if (lane == 0) out[0] = v / (float)(Q * KNN);
}

extern "C" void kernel_launch(void* const* d_in, const int* in_sizes, int n_in,
                              void* d_out, int out_size, void* d_ws, size_t ws_size,
                              hipStream_t stream) {
    (void)n_in; (void)out_size; (void)ws_size;
    const float* emb = (const float*)d_in[0];
    const float* mem = (const float*)d_in[1];
    const int Q   = in_sizes[0] / DDIM;       // 256
    const int N   = in_sizes[1] / DDIM;       // 200000
    const int NCH = (N + CROWS - 1) / CROWS;  // 782

    float*          cand  = (float*)d_ws;                                        // Q*NCH*5*4B ~ 4 MB
    float*          qsum  = (float*)((char*)d_ws + (size_t)Q * NCH * KNN * 4);   // 1 KB
    unsigned short* qfrag = (unsigned short*)((char*)d_ws + (size_t)Q * NCH * KNN * 4 + 1024);

    conv_q<<<64, 256, 0, stream>>>(emb, qfrag);
    knn_partial<<<NCH * 2, NT, 0, stream>>>(mem, qfrag, cand, N, NCH);
    knn_merge_exact<<<Q, 64, 0, stream>>>(emb, mem, cand, qsum, Q, NCH);
    knn_reduce<<<1, 64, 0, stream>>>(qsum, (float*)d_out, Q);
}